// Round 8
// baseline (181.142 us; speedup 1.0000x reference)
//
#include <hip/hip_runtime.h>

typedef unsigned short ushort_t;
typedef __attribute__((ext_vector_type(8))) short bf16x8;
typedef __attribute__((ext_vector_type(4))) float f32x4;

__device__ __forceinline__ float bf2f(ushort_t u) {
    union { unsigned int i; float f; } v; v.i = ((unsigned int)u) << 16; return v.f;
}
__device__ __forceinline__ ushort_t f2bf(float f) {
    union { float f; unsigned int i; } v; v.f = f;
    unsigned int r = v.i + 0x7FFFu + ((v.i >> 16) & 1u);   // RNE
    return (ushort_t)(r >> 16);
}

// Problem constants: B=16, C=64, H=W=80, s=2, Hs=Ws=160. fp32 I/O.
#define BB 16
#define CC 64
#define HH 80
#define WW 80
#define HS 160
#define WS 160
#define HW (HH*WW)          // 6400
#define HWS (HS*WS)         // 25600

// ---------------------------------------------------------------------------
// prep_x: fused transpose (x fp32 -> xT bf16 channel-last) + low-res 12-ch conv
//  - 12-ch conv weights built in LDS from offset_w/mask_w (no prep kernel)
//  - x loads: float4 (16 B/lane), xT stores: 2 dwords = 4 packed bf16 per iter
// ---------------------------------------------------------------------------
__global__ __launch_bounds__(256) void prep_x(const float* __restrict__ x,
                                              const float* __restrict__ offset_w,
                                              const float* __restrict__ offset_b,
                                              const float* __restrict__ mask_w,
                                              const float* __restrict__ mask_b,
                                              ushort_t* __restrict__ xT,
                                              float* __restrict__ offs) {
    __shared__ float sX[64 * 65];   // [px][c]
    __shared__ float sW[12 * 64 + 12];   // wmat rows + bias tail
    int t = threadIdx.x;
    int tile = blockIdx.x;          // 0..1599
    int b = tile / 100;             // 100 tiles of 64 px per image
    int hw0 = (tile - b * 100) * 64;
    const float* xb = x + (size_t)b * CC * HW + hw0;

    // stage conv weights (identical values to old prep_params wmat/wbias)
    for (int i = t; i < 12 * 64; i += 256) {
        int ch = i >> 6, c = i & 63;
        sW[i] = ch < 8 ? offset_w[ch * 64 + c] : mask_w[(ch - 8) * 64 + c];
    }
    if (t < 12) sW[768 + t] = t < 8 ? offset_b[t] : mask_b[t - 8];

    // load 64ch x 64px tile as float4: e=(k*256+t) -> c=e>>4, j4=(e&15)*4
#pragma unroll
    for (int k = 0; k < 4; ++k) {
        int e = k * 256 + t;                 // 0..1023
        int c = e >> 4, j4 = (e & 15) << 2;  // channel, px-quad base
        f32x4 v = *(const f32x4*)(xb + (size_t)c * HW + j4);   // 16B aligned
        sX[(j4 + 0) * 65 + c] = v.x;
        sX[(j4 + 1) * 65 + c] = v.y;
        sX[(j4 + 2) * 65 + c] = v.z;
        sX[(j4 + 3) * 65 + c] = v.w;
    }
    __syncthreads();

    // transpose write: e -> j=e>>4, c4=(e&15)*4; pack 4 bf16 -> 2 dword stores
    size_t xtb = ((size_t)(b * HW) + hw0) * CC;
#pragma unroll
    for (int k = 0; k < 4; ++k) {
        int e = k * 256 + t;
        int j = e >> 4, c4 = (e & 15) << 2;
        const float* rp = sX + j * 65 + c4;
        unsigned int u0 = (unsigned int)f2bf(rp[0]) | ((unsigned int)f2bf(rp[1]) << 16);
        unsigned int u1 = (unsigned int)f2bf(rp[2]) | ((unsigned int)f2bf(rp[3]) << 16);
        unsigned int* dst = (unsigned int*)(xT + xtb + (size_t)j * CC + c4);
        dst[0] = u0;
        dst[1] = u1;
    }

    // 12-channel conv: lane=px, 4 waves x 3 channels; weights from LDS
    int px = t & 63;
    int chunk = __builtin_amdgcn_readfirstlane(t >> 6);
    int ch0 = chunk * 3;
    const float* w0 = sW + (ch0 + 0) * 64;
    const float* w1 = sW + (ch0 + 1) * 64;
    const float* w2 = sW + (ch0 + 2) * 64;
    float a0 = 0.f, a1 = 0.f, a2 = 0.f;
#pragma unroll 4
    for (int c = 0; c < 64; ++c) {
        float v = sX[px * 65 + c];
        a0 += v * w0[c];
        a1 += v * w1[c];
        a2 += v * w2[c];
    }
    a0 += sW[768 + ch0 + 0];
    a1 += sW[768 + ch0 + 1];
    a2 += sW[768 + ch0 + 2];
    if (ch0 + 0 >= 8) a0 = 1.0f / (1.0f + __expf(-a0));
    if (ch0 + 1 >= 8) a1 = 1.0f / (1.0f + __expf(-a1));
    if (ch0 + 2 >= 8) a2 = 1.0f / (1.0f + __expf(-a2));
    float* op = offs + (size_t)(b * HW + hw0 + px) * 12;
    op[ch0 + 0] = a0;
    op[ch0 + 1] = a1;
    op[ch0 + 2] = a2;
}

// ---------------------------------------------------------------------------
// axis taps: compose grid_sample (160-grid, zero pad) with 2x bilinear
// upsample (80-grid, edge clamp) -> 3-wide window [base, base+2], base∈[0,77].
// ---------------------------------------------------------------------------
#define ACC3(w, k, val) { float _v = (val); \
    w[0] += (k) == 0 ? _v : 0.f; w[1] += (k) == 1 ? _v : 0.f; w[2] += (k) == 2 ? _v : 0.f; }

__device__ __forceinline__ void axis_taps(float pos, int& base, float w[3]) {
    float f = floorf(pos); int u0 = (int)f; float g1 = pos - f;
    w[0] = w[1] = w[2] = 0.f;
    bool v0 = (u0 >= 0) & (u0 < 160);
    bool v1 = (u0 + 1 >= 0) & (u0 + 1 < 160);
    float cc0 = 0.f, cc1 = 0.f; int ca0 = 0, ca1 = 0;
    if (v0) { cc0 = fminf(fmaxf((float)u0 * 0.5f - 0.25f, 0.f), 79.f); ca0 = (int)floorf(cc0); }
    if (v1) { cc1 = fminf(fmaxf((float)(u0 + 1) * 0.5f - 0.25f, 0.f), 79.f); ca1 = (int)floorf(cc1); }
    int first = v0 ? ca0 : (v1 ? ca1 : 0);
    base = min(first, 77);
    if (v0) {
        float wv = cc0 - (float)ca0; int c1 = min(ca0 + 1, 79);
        int k0 = ca0 - base, k1 = c1 - base;
        ACC3(w, k0, (1.f - g1) * (1.f - wv));
        ACC3(w, k1, (1.f - g1) * wv);
    }
    if (v1) {
        float wv = cc1 - (float)ca1; int c1 = min(ca1 + 1, 79);
        int k0 = ca1 - base, k1 = c1 - base;
        ACC3(w, k0, g1 * (1.f - wv));
        ACC3(w, k1, g1 * wv);
    }
}

// ---------------------------------------------------------------------------
// main: 64 output pixels per block (flat tiling, no dead slots).
// XCD swizzle: lx = (bx&7)*50 + bx>>3 (bijective, 400=8*50).
// Preamble: each wave converts its own conv_w slice (fp32->bf16, same f2bf as
//           old prep_params) and computes its 4 BN coefficients.
// Phase 0: distributed taps — lanes 0..15 of wave w compute px w*16..w*16+15.
// Phase 1: both px-passes fully unrolled; all 18 bf16x8 gathers issued
//          back-to-back before consumption.
// Phase 2: MFMA 16x16x32 bf16: D[cout][px] = W[cout][cin] * S[cin][px]; BN+SiLU.
// ---------------------------------------------------------------------------
__global__ __launch_bounds__(256) void dysample_main(const ushort_t* __restrict__ xT,
                                                     const float* __restrict__ offs,
                                                     const float* __restrict__ conv_w,
                                                     const float* __restrict__ gamma,
                                                     const float* __restrict__ beta,
                                                     const float* __restrict__ mean,
                                                     const float* __restrict__ var,
                                                     float* __restrict__ out) {
    __shared__ float sTap[64 * 8];       // bits(cb|rb<<16), cw0..2, rw0..2, mask
    __shared__ ushort_t S[64 * 72];      // [px][cin], stride 72 (16B-aligned rows)
    int t = threadIdx.x;
    int lane = t & 63;
    int wave = __builtin_amdgcn_readfirstlane(t >> 6);
    int quad = lane >> 4, nrow = lane & 15;
    int b = blockIdx.y;
    int bx = blockIdx.x;
    int lx = ((bx & 7) * 50) + (bx >> 3);   // XCD-chunked bijective swizzle (400=8*50)
    int pix0 = lx * 64;

    // preamble: conv_w slice fp32 -> bf16 A-fragments (identical f2bf math) + BN
    const float* wrow = conv_w + (wave * 16 + nrow) * 64 + quad * 8;
    f32x4 wf0 = *(const f32x4*)(wrow);
    f32x4 wf1 = *(const f32x4*)(wrow + 4);
    f32x4 wf2 = *(const f32x4*)(wrow + 32);
    f32x4 wf3 = *(const f32x4*)(wrow + 36);
    bf16x8 af0, af1;
#pragma unroll
    for (int j = 0; j < 4; ++j) {
        af0[j]     = (short)f2bf(wf0[j]);
        af0[4 + j] = (short)f2bf(wf1[j]);
        af1[j]     = (short)f2bf(wf2[j]);
        af1[4 + j] = (short)f2bf(wf3[j]);
    }
    int coutD = wave * 16 + quad * 4;
    float bnAv[4], bnBv[4];
#pragma unroll
    for (int j = 0; j < 4; ++j) {
        float A = gamma[coutD + j] * rsqrtf(var[coutD + j] + 1e-5f);
        bnAv[j] = A;
        bnBv[j] = beta[coutD + j] - mean[coutD + j] * A;
    }

    // ---- phase 0: distributed taps (each wave's lanes 0..15 own its 16 px)
    if (lane < 16) {
        int pxl = (wave << 4) | lane;
        int pix = pix0 + pxl;
        int ho = pix / WS, wo = pix - ho * WS;
        int h = ho >> 1, w = wo >> 1, r = ((ho & 1) << 1) | (wo & 1);
        const float* op = offs + (size_t)((b * HW) + h * WW + w) * 12;
        float ox = op[r], oy = op[4 + r], mk = op[8 + r];
        // ix = ((gx+1)*160-1)*0.5 with gx = -1 + wo*2/159 + ox
        float ix = (float)wo * (160.0f / 159.0f) - 0.5f + 80.0f * ox;
        float iy = (float)ho * (160.0f / 159.0f) - 0.5f + 80.0f * oy;
        int cb, rb; float cw[3], rw[3];
        axis_taps(ix, cb, cw);
        axis_taps(iy, rb, rw);
        sTap[pxl * 8 + 0] = __int_as_float(cb | (rb << 16));
        sTap[pxl * 8 + 1] = cw[0]; sTap[pxl * 8 + 2] = cw[1]; sTap[pxl * 8 + 3] = cw[2];
        sTap[pxl * 8 + 4] = rw[0]; sTap[pxl * 8 + 5] = rw[1]; sTap[pxl * 8 + 6] = rw[2];
        sTap[pxl * 8 + 7] = mk;
    }
    __syncthreads();

    // ---- phase 1: lane = (px-octet, channel-octet); both passes unrolled,
    //      all 18 loads issued before any use.
    int sub8 = lane >> 3;            // 0..7 px sub-index
    int g8 = (lane & 7) << 3;        // channel base 0,8,...,56
    const ushort_t* xb = xT + (size_t)b * HW * CC;

    int pxA = wave * 16 + sub8;
    int pxB = wave * 16 + 8 + sub8;
    f32x4 tA0 = *(const f32x4*)(sTap + pxA * 8);
    f32x4 tA1 = *(const f32x4*)(sTap + pxA * 8 + 4);
    f32x4 tB0 = *(const f32x4*)(sTap + pxB * 8);
    f32x4 tB1 = *(const f32x4*)(sTap + pxB * 8 + 4);
    int bitsA = __float_as_int(tA0.x);
    int cbA = bitsA & 0xffff, rbA = bitsA >> 16;
    int bitsB = __float_as_int(tB0.x);
    int cbB = bitsB & 0xffff, rbB = bitsB >> 16;
    const ushort_t* pA = xb + (rbA * WW + cbA) * CC + g8;   // 16B aligned
    const ushort_t* pB = xb + (rbB * WW + cbB) * CC + g8;

    // 18 gathers, back-to-back
    bf16x8 a00 = *(const bf16x8*)(pA);
    bf16x8 a01 = *(const bf16x8*)(pA + CC);
    bf16x8 a02 = *(const bf16x8*)(pA + 2 * CC);
    bf16x8 a10 = *(const bf16x8*)(pA + WW * CC);
    bf16x8 a11 = *(const bf16x8*)(pA + WW * CC + CC);
    bf16x8 a12 = *(const bf16x8*)(pA + WW * CC + 2 * CC);
    bf16x8 a20 = *(const bf16x8*)(pA + 2 * WW * CC);
    bf16x8 a21 = *(const bf16x8*)(pA + 2 * WW * CC + CC);
    bf16x8 a22 = *(const bf16x8*)(pA + 2 * WW * CC + 2 * CC);
    bf16x8 b00 = *(const bf16x8*)(pB);
    bf16x8 b01 = *(const bf16x8*)(pB + CC);
    bf16x8 b02 = *(const bf16x8*)(pB + 2 * CC);
    bf16x8 b10 = *(const bf16x8*)(pB + WW * CC);
    bf16x8 b11 = *(const bf16x8*)(pB + WW * CC + CC);
    bf16x8 b12 = *(const bf16x8*)(pB + WW * CC + 2 * CC);
    bf16x8 b20 = *(const bf16x8*)(pB + 2 * WW * CC);
    bf16x8 b21 = *(const bf16x8*)(pB + 2 * WW * CC + CC);
    bf16x8 b22 = *(const bf16x8*)(pB + 2 * WW * CC + 2 * CC);

    // pass A: weight(rr,c) = rw[rr]*cw[c]; t0.yzw = cw, t1.xyz = rw
    {
        float w00 = tA1.x * tA0.y, w01 = tA1.x * tA0.z, w02 = tA1.x * tA0.w;
        float w10 = tA1.y * tA0.y, w11 = tA1.y * tA0.z, w12 = tA1.y * tA0.w;
        float w20 = tA1.z * tA0.y, w21 = tA1.z * tA0.z, w22 = tA1.z * tA0.w;
        bf16x8 outv;
#pragma unroll
        for (int j = 0; j < 8; ++j) {
            float a = w00 * bf2f((ushort_t)a00[j]) + w01 * bf2f((ushort_t)a01[j])
                    + w02 * bf2f((ushort_t)a02[j])
                    + w10 * bf2f((ushort_t)a10[j]) + w11 * bf2f((ushort_t)a11[j])
                    + w12 * bf2f((ushort_t)a12[j])
                    + w20 * bf2f((ushort_t)a20[j]) + w21 * bf2f((ushort_t)a21[j])
                    + w22 * bf2f((ushort_t)a22[j]);
            outv[j] = (short)f2bf(a * tA1.w);
        }
        *(bf16x8*)(S + pxA * 72 + g8) = outv;    // short-typed, 16B aligned
    }
    // pass B
    {
        float w00 = tB1.x * tB0.y, w01 = tB1.x * tB0.z, w02 = tB1.x * tB0.w;
        float w10 = tB1.y * tB0.y, w11 = tB1.y * tB0.z, w12 = tB1.y * tB0.w;
        float w20 = tB1.z * tB0.y, w21 = tB1.z * tB0.z, w22 = tB1.z * tB0.w;
        bf16x8 outv;
#pragma unroll
        for (int j = 0; j < 8; ++j) {
            float a = w00 * bf2f((ushort_t)b00[j]) + w01 * bf2f((ushort_t)b01[j])
                    + w02 * bf2f((ushort_t)b02[j])
                    + w10 * bf2f((ushort_t)b10[j]) + w11 * bf2f((ushort_t)b11[j])
                    + w12 * bf2f((ushort_t)b12[j])
                    + w20 * bf2f((ushort_t)b20[j]) + w21 * bf2f((ushort_t)b21[j])
                    + w22 * bf2f((ushort_t)b22[j]);
            outv[j] = (short)f2bf(a * tB1.w);
        }
        *(bf16x8*)(S + pxB * 72 + g8) = outv;
    }
    __syncthreads();

    // ---- phase 2: D[cout][px] via MFMA; wave = cout tile
    f32x4 acc4[4];
#pragma unroll
    for (int n = 0; n < 4; ++n) acc4[n] = (f32x4){0.f, 0.f, 0.f, 0.f};
#pragma unroll
    for (int n = 0; n < 4; ++n) {
        const ushort_t* sp = S + (n * 16 + nrow) * 72 + quad * 8;
        bf16x8 b0 = *(const bf16x8*)(sp);        // k = 0..31
        bf16x8 b1 = *(const bf16x8*)(sp + 32);   // k = 32..63
        acc4[n] = __builtin_amdgcn_mfma_f32_16x16x32_bf16(af0, b0, acc4[n], 0, 0, 0);
        acc4[n] = __builtin_amdgcn_mfma_f32_16x16x32_bf16(af1, b1, acc4[n], 0, 0, 0);
    }

    // epilogue: BN + SiLU + store (16 px contiguous per quad-group)
    size_t ob = (size_t)b * CC * HWS;
#pragma unroll
    for (int n = 0; n < 4; ++n) {
        int pix = pix0 + n * 16 + nrow;
#pragma unroll
        for (int j = 0; j < 4; ++j) {
            float y = acc4[n][j] * bnAv[j] + bnBv[j];
            float s = y / (1.0f + __expf(-y));
            out[ob + (size_t)(coutD + j) * HWS + pix] = s;
        }
    }
}

// ---------------------------------------------------------------------------
extern "C" void kernel_launch(void* const* d_in, const int* in_sizes, int n_in,
                              void* d_out, int out_size, void* d_ws, size_t ws_size,
                              hipStream_t stream) {
    const float* x        = (const float*)d_in[0];
    const float* offset_w = (const float*)d_in[1];
    const float* offset_b = (const float*)d_in[2];
    const float* mask_w   = (const float*)d_in[3];
    const float* mask_b   = (const float*)d_in[4];
    const float* conv_w   = (const float*)d_in[5];
    const float* bn_gamma = (const float*)d_in[6];
    const float* bn_beta  = (const float*)d_in[7];
    const float* bn_mean  = (const float*)d_in[8];
    const float* bn_var   = (const float*)d_in[9];

    char* ws = (char*)d_ws;
    size_t off = 0;
    ushort_t* xT   = (ushort_t*)(ws + off); off += (size_t)BB * HW * CC * 2;   // 13.1 MB
    float*    offs = (float*)(ws + off);    off += (size_t)BB * HW * 12 * 4;   //  4.9 MB

    prep_x<<<BB * (HW / 64), 256, 0, stream>>>(x, offset_w, offset_b, mask_w, mask_b,
                                               xT, offs);
    dysample_main<<<dim3(HWS / 64, BB), 256, 0, stream>>>(xT, offs, conv_w,
                                                          bn_gamma, bn_beta, bn_mean,
                                                          bn_var, (float*)d_out);
}

// Round 9
// 177.169 us; speedup vs baseline: 1.0224x; 1.0224x over previous
//
#include <hip/hip_runtime.h>

typedef unsigned short ushort_t;
typedef __attribute__((ext_vector_type(8))) short bf16x8;
typedef __attribute__((ext_vector_type(4))) float f32x4;

__device__ __forceinline__ float bf2f(ushort_t u) {
    union { unsigned int i; float f; } v; v.i = ((unsigned int)u) << 16; return v.f;
}
__device__ __forceinline__ ushort_t f2bf(float f) {
    union { float f; unsigned int i; } v; v.f = f;
    unsigned int r = v.i + 0x7FFFu + ((v.i >> 16) & 1u);   // RNE
    return (ushort_t)(r >> 16);
}

// Problem constants: B=16, C=64, H=W=80, s=2, Hs=Ws=160. fp32 I/O.
#define BB 16
#define CC 64
#define HH 80
#define WW 80
#define HS 160
#define WS 160
#define HW (HH*WW)          // 6400
#define HWS (HS*WS)         // 25600

// ---------------------------------------------------------------------------
// prep_params: wmat[12][64], wbias[12], cwBf[cout][cin] bf16, bnA/bnB fp32
// (one-time cost; keeps per-block work out of the 6400-block main kernel)
// ---------------------------------------------------------------------------
__global__ void prep_params(const float* __restrict__ offset_w,
                            const float* __restrict__ offset_b,
                            const float* __restrict__ mask_w,
                            const float* __restrict__ mask_b,
                            const float* __restrict__ conv_w,
                            const float* __restrict__ gamma,
                            const float* __restrict__ beta,
                            const float* __restrict__ mean,
                            const float* __restrict__ var,
                            float* __restrict__ wmat, float* __restrict__ wbias,
                            ushort_t* __restrict__ cwBf,
                            float* __restrict__ bnA, float* __restrict__ bnB) {
    int t = threadIdx.x;
    for (int i = t; i < 12 * 64; i += 256) {
        int ch = i >> 6, c = i & 63;
        wmat[i] = ch < 8 ? offset_w[ch * 64 + c] : mask_w[(ch - 8) * 64 + c];
    }
    if (t < 12) wbias[t] = t < 8 ? offset_b[t] : mask_b[t - 8];
    for (int i = t; i < 64 * 64; i += 256) cwBf[i] = f2bf(conv_w[i]);  // [o][c] row-major
    if (t < 64) {
        float A = gamma[t] * rsqrtf(var[t] + 1e-5f);
        bnA[t] = A;
        bnB[t] = beta[t] - mean[t] * A;
    }
}

// ---------------------------------------------------------------------------
// prep_x: fused transpose (x fp32 -> xT bf16 channel-last) + low-res 12-ch conv
//  - x loads: float4 (16 B/lane), xT stores: 2 dwords = 4 packed bf16 per iter
// ---------------------------------------------------------------------------
__global__ __launch_bounds__(256) void prep_x(const float* __restrict__ x,
                                              const float* __restrict__ wmat,
                                              const float* __restrict__ wbias,
                                              ushort_t* __restrict__ xT,
                                              float* __restrict__ offs) {
    __shared__ float sX[64 * 65];   // [px][c]
    int t = threadIdx.x;
    int tile = blockIdx.x;          // 0..1599
    int b = tile / 100;             // 100 tiles of 64 px per image
    int hw0 = (tile - b * 100) * 64;
    const float* xb = x + (size_t)b * CC * HW + hw0;

    // load 64ch x 64px tile as float4: e=(k*256+t) -> c=e>>4, j4=(e&15)*4
#pragma unroll
    for (int k = 0; k < 4; ++k) {
        int e = k * 256 + t;                 // 0..1023
        int c = e >> 4, j4 = (e & 15) << 2;  // channel, px-quad base
        f32x4 v = *(const f32x4*)(xb + (size_t)c * HW + j4);   // 16B aligned
        sX[(j4 + 0) * 65 + c] = v.x;
        sX[(j4 + 1) * 65 + c] = v.y;
        sX[(j4 + 2) * 65 + c] = v.z;
        sX[(j4 + 3) * 65 + c] = v.w;
    }
    __syncthreads();

    // transpose write: e -> j=e>>4, c4=(e&15)*4; pack 4 bf16 -> 2 dword stores
    size_t xtb = ((size_t)(b * HW) + hw0) * CC;
#pragma unroll
    for (int k = 0; k < 4; ++k) {
        int e = k * 256 + t;
        int j = e >> 4, c4 = (e & 15) << 2;
        const float* rp = sX + j * 65 + c4;
        unsigned int u0 = (unsigned int)f2bf(rp[0]) | ((unsigned int)f2bf(rp[1]) << 16);
        unsigned int u1 = (unsigned int)f2bf(rp[2]) | ((unsigned int)f2bf(rp[3]) << 16);
        unsigned int* dst = (unsigned int*)(xT + xtb + (size_t)j * CC + c4);
        dst[0] = u0;
        dst[1] = u1;
    }

    // 12-channel conv: lane=px, 4 waves x 3 channels (unchanged)
    int px = t & 63;
    int chunk = __builtin_amdgcn_readfirstlane(t >> 6);
    int ch0 = chunk * 3;
    const float* w0 = wmat + (ch0 + 0) * 64;
    const float* w1 = wmat + (ch0 + 1) * 64;
    const float* w2 = wmat + (ch0 + 2) * 64;
    float a0 = 0.f, a1 = 0.f, a2 = 0.f;
#pragma unroll 4
    for (int c = 0; c < 64; ++c) {
        float v = sX[px * 65 + c];
        a0 += v * w0[c];
        a1 += v * w1[c];
        a2 += v * w2[c];
    }
    a0 += wbias[ch0 + 0];
    a1 += wbias[ch0 + 1];
    a2 += wbias[ch0 + 2];
    if (ch0 + 0 >= 8) a0 = 1.0f / (1.0f + __expf(-a0));
    if (ch0 + 1 >= 8) a1 = 1.0f / (1.0f + __expf(-a1));
    if (ch0 + 2 >= 8) a2 = 1.0f / (1.0f + __expf(-a2));
    float* op = offs + (size_t)(b * HW + hw0 + px) * 12;
    op[ch0 + 0] = a0;
    op[ch0 + 1] = a1;
    op[ch0 + 2] = a2;
}

// ---------------------------------------------------------------------------
// axis taps: compose grid_sample (160-grid, zero pad) with 2x bilinear
// upsample (80-grid, edge clamp) -> 3-wide window [base, base+2], base∈[0,77].
// ---------------------------------------------------------------------------
#define ACC3(w, k, val) { float _v = (val); \
    w[0] += (k) == 0 ? _v : 0.f; w[1] += (k) == 1 ? _v : 0.f; w[2] += (k) == 2 ? _v : 0.f; }

__device__ __forceinline__ void axis_taps(float pos, int& base, float w[3]) {
    float f = floorf(pos); int u0 = (int)f; float g1 = pos - f;
    w[0] = w[1] = w[2] = 0.f;
    bool v0 = (u0 >= 0) & (u0 < 160);
    bool v1 = (u0 + 1 >= 0) & (u0 + 1 < 160);
    float cc0 = 0.f, cc1 = 0.f; int ca0 = 0, ca1 = 0;
    if (v0) { cc0 = fminf(fmaxf((float)u0 * 0.5f - 0.25f, 0.f), 79.f); ca0 = (int)floorf(cc0); }
    if (v1) { cc1 = fminf(fmaxf((float)(u0 + 1) * 0.5f - 0.25f, 0.f), 79.f); ca1 = (int)floorf(cc1); }
    int first = v0 ? ca0 : (v1 ? ca1 : 0);
    base = min(first, 77);
    if (v0) {
        float wv = cc0 - (float)ca0; int c1 = min(ca0 + 1, 79);
        int k0 = ca0 - base, k1 = c1 - base;
        ACC3(w, k0, (1.f - g1) * (1.f - wv));
        ACC3(w, k1, (1.f - g1) * wv);
    }
    if (v1) {
        float wv = cc1 - (float)ca1; int c1 = min(ca1 + 1, 79);
        int k0 = ca1 - base, k1 = c1 - base;
        ACC3(w, k0, g1 * (1.f - wv));
        ACC3(w, k1, g1 * wv);
    }
}

// ---------------------------------------------------------------------------
// main: 64 output pixels per block (flat tiling, no dead slots).
// XCD swizzle: lx = (bx&7)*50 + bx>>3 (bijective, 400=8*50).
// Phase 0: PER-WAVE taps — lanes 0..15 of wave w compute px w*16..w*16+15.
//   Wave w's phase 1 reads ONLY its own 16 px taps -> producer and consumer
//   are the same wave -> NO barrier needed (same-wave LDS ops are in-order;
//   compiler inserts the lgkmcnt wait for the sTap RAW).
// Phase 1: both px-passes fully unrolled; all 18 bf16x8 gathers issued
//          back-to-back before consumption.
// Phase 2: MFMA 16x16x32 bf16 (cross-wave S reads -> barrier kept); BN+SiLU.
// ---------------------------------------------------------------------------
__global__ __launch_bounds__(256) void dysample_main(const ushort_t* __restrict__ xT,
                                                     const float* __restrict__ offs,
                                                     const ushort_t* __restrict__ cwBf,
                                                     const float* __restrict__ bnA,
                                                     const float* __restrict__ bnB,
                                                     float* __restrict__ out) {
    __shared__ float sTap[64 * 8];       // bits(cb|rb<<16), cw0..2, rw0..2, mask
    __shared__ ushort_t S[64 * 72];      // [px][cin], stride 72 (16B-aligned rows)
    int t = threadIdx.x;
    int lane = t & 63;
    int wave = __builtin_amdgcn_readfirstlane(t >> 6);
    int quad = lane >> 4, nrow = lane & 15;
    int b = blockIdx.y;
    int bx = blockIdx.x;
    int lx = ((bx & 7) * 50) + (bx >> 3);   // XCD-chunked bijective swizzle (400=8*50)
    int pix0 = lx * 64;

    // preload A-fragments (conv weights, bf16) + BN params for this wave's couts
    const ushort_t* wp = cwBf + (wave * 16 + nrow) * 64 + quad * 8;
    bf16x8 af0 = *(const bf16x8*)(wp);
    bf16x8 af1 = *(const bf16x8*)(wp + 32);
    int coutD = wave * 16 + quad * 4;
    float bnAv[4], bnBv[4];
#pragma unroll
    for (int j = 0; j < 4; ++j) { bnAv[j] = bnA[coutD + j]; bnBv[j] = bnB[coutD + j]; }

    // ---- phase 0: per-wave taps (lanes 0..15 own this wave's 16 px); no barrier
    if (lane < 16) {
        int pxl = (wave << 4) | lane;
        int pix = pix0 + pxl;
        int ho = pix / WS, wo = pix - ho * WS;
        int h = ho >> 1, w = wo >> 1, r = ((ho & 1) << 1) | (wo & 1);
        const float* op = offs + (size_t)((b * HW) + h * WW + w) * 12;
        float ox = op[r], oy = op[4 + r], mk = op[8 + r];
        // ix = ((gx+1)*160-1)*0.5 with gx = -1 + wo*2/159 + ox
        float ix = (float)wo * (160.0f / 159.0f) - 0.5f + 80.0f * ox;
        float iy = (float)ho * (160.0f / 159.0f) - 0.5f + 80.0f * oy;
        int cb, rb; float cw[3], rw[3];
        axis_taps(ix, cb, cw);
        axis_taps(iy, rb, rw);
        sTap[pxl * 8 + 0] = __int_as_float(cb | (rb << 16));
        sTap[pxl * 8 + 1] = cw[0]; sTap[pxl * 8 + 2] = cw[1]; sTap[pxl * 8 + 3] = cw[2];
        sTap[pxl * 8 + 4] = rw[0]; sTap[pxl * 8 + 5] = rw[1]; sTap[pxl * 8 + 6] = rw[2];
        sTap[pxl * 8 + 7] = mk;
    }
    // no __syncthreads(): wave w reads only sTap rows it just wrote

    // ---- phase 1: lane = (px-octet, channel-octet); both passes unrolled,
    //      all 18 loads issued before any use.
    int sub8 = lane >> 3;            // 0..7 px sub-index
    int g8 = (lane & 7) << 3;        // channel base 0,8,...,56
    const ushort_t* xb = xT + (size_t)b * HW * CC;

    int pxA = wave * 16 + sub8;
    int pxB = wave * 16 + 8 + sub8;
    f32x4 tA0 = *(const f32x4*)(sTap + pxA * 8);
    f32x4 tA1 = *(const f32x4*)(sTap + pxA * 8 + 4);
    f32x4 tB0 = *(const f32x4*)(sTap + pxB * 8);
    f32x4 tB1 = *(const f32x4*)(sTap + pxB * 8 + 4);
    int bitsA = __float_as_int(tA0.x);
    int cbA = bitsA & 0xffff, rbA = bitsA >> 16;
    int bitsB = __float_as_int(tB0.x);
    int cbB = bitsB & 0xffff, rbB = bitsB >> 16;
    const ushort_t* pA = xb + (rbA * WW + cbA) * CC + g8;   // 16B aligned
    const ushort_t* pB = xb + (rbB * WW + cbB) * CC + g8;

    // 18 gathers, back-to-back
    bf16x8 a00 = *(const bf16x8*)(pA);
    bf16x8 a01 = *(const bf16x8*)(pA + CC);
    bf16x8 a02 = *(const bf16x8*)(pA + 2 * CC);
    bf16x8 a10 = *(const bf16x8*)(pA + WW * CC);
    bf16x8 a11 = *(const bf16x8*)(pA + WW * CC + CC);
    bf16x8 a12 = *(const bf16x8*)(pA + WW * CC + 2 * CC);
    bf16x8 a20 = *(const bf16x8*)(pA + 2 * WW * CC);
    bf16x8 a21 = *(const bf16x8*)(pA + 2 * WW * CC + CC);
    bf16x8 a22 = *(const bf16x8*)(pA + 2 * WW * CC + 2 * CC);
    bf16x8 b00 = *(const bf16x8*)(pB);
    bf16x8 b01 = *(const bf16x8*)(pB + CC);
    bf16x8 b02 = *(const bf16x8*)(pB + 2 * CC);
    bf16x8 b10 = *(const bf16x8*)(pB + WW * CC);
    bf16x8 b11 = *(const bf16x8*)(pB + WW * CC + CC);
    bf16x8 b12 = *(const bf16x8*)(pB + WW * CC + 2 * CC);
    bf16x8 b20 = *(const bf16x8*)(pB + 2 * WW * CC);
    bf16x8 b21 = *(const bf16x8*)(pB + 2 * WW * CC + CC);
    bf16x8 b22 = *(const bf16x8*)(pB + 2 * WW * CC + 2 * CC);

    // pass A: weight(rr,c) = rw[rr]*cw[c]; t0.yzw = cw, t1.xyz = rw
    {
        float w00 = tA1.x * tA0.y, w01 = tA1.x * tA0.z, w02 = tA1.x * tA0.w;
        float w10 = tA1.y * tA0.y, w11 = tA1.y * tA0.z, w12 = tA1.y * tA0.w;
        float w20 = tA1.z * tA0.y, w21 = tA1.z * tA0.z, w22 = tA1.z * tA0.w;
        bf16x8 outv;
#pragma unroll
        for (int j = 0; j < 8; ++j) {
            float a = w00 * bf2f((ushort_t)a00[j]) + w01 * bf2f((ushort_t)a01[j])
                    + w02 * bf2f((ushort_t)a02[j])
                    + w10 * bf2f((ushort_t)a10[j]) + w11 * bf2f((ushort_t)a11[j])
                    + w12 * bf2f((ushort_t)a12[j])
                    + w20 * bf2f((ushort_t)a20[j]) + w21 * bf2f((ushort_t)a21[j])
                    + w22 * bf2f((ushort_t)a22[j]);
            outv[j] = (short)f2bf(a * tA1.w);
        }
        *(bf16x8*)(S + pxA * 72 + g8) = outv;    // short-typed, 16B aligned
    }
    // pass B
    {
        float w00 = tB1.x * tB0.y, w01 = tB1.x * tB0.z, w02 = tB1.x * tB0.w;
        float w10 = tB1.y * tB0.y, w11 = tB1.y * tB0.z, w12 = tB1.y * tB0.w;
        float w20 = tB1.z * tB0.y, w21 = tB1.z * tB0.z, w22 = tB1.z * tB0.w;
        bf16x8 outv;
#pragma unroll
        for (int j = 0; j < 8; ++j) {
            float a = w00 * bf2f((ushort_t)b00[j]) + w01 * bf2f((ushort_t)b01[j])
                    + w02 * bf2f((ushort_t)b02[j])
                    + w10 * bf2f((ushort_t)b10[j]) + w11 * bf2f((ushort_t)b11[j])
                    + w12 * bf2f((ushort_t)b12[j])
                    + w20 * bf2f((ushort_t)b20[j]) + w21 * bf2f((ushort_t)b21[j])
                    + w22 * bf2f((ushort_t)b22[j]);
            outv[j] = (short)f2bf(a * tB1.w);
        }
        *(bf16x8*)(S + pxB * 72 + g8) = outv;
    }
    __syncthreads();   // S is read cross-wave in phase 2

    // ---- phase 2: D[cout][px] via MFMA; wave = cout tile
    f32x4 acc4[4];
#pragma unroll
    for (int n = 0; n < 4; ++n) acc4[n] = (f32x4){0.f, 0.f, 0.f, 0.f};
#pragma unroll
    for (int n = 0; n < 4; ++n) {
        const ushort_t* sp = S + (n * 16 + nrow) * 72 + quad * 8;
        bf16x8 b0 = *(const bf16x8*)(sp);        // k = 0..31
        bf16x8 b1 = *(const bf16x8*)(sp + 32);   // k = 32..63
        acc4[n] = __builtin_amdgcn_mfma_f32_16x16x32_bf16(af0, b0, acc4[n], 0, 0, 0);
        acc4[n] = __builtin_amdgcn_mfma_f32_16x16x32_bf16(af1, b1, acc4[n], 0, 0, 0);
    }

    // epilogue: BN + SiLU + store (16 px contiguous per quad-group)
    size_t ob = (size_t)b * CC * HWS;
#pragma unroll
    for (int n = 0; n < 4; ++n) {
        int pix = pix0 + n * 16 + nrow;
#pragma unroll
        for (int j = 0; j < 4; ++j) {
            float y = acc4[n][j] * bnAv[j] + bnBv[j];
            float s = y / (1.0f + __expf(-y));
            out[ob + (size_t)(coutD + j) * HWS + pix] = s;
        }
    }
}

// ---------------------------------------------------------------------------
extern "C" void kernel_launch(void* const* d_in, const int* in_sizes, int n_in,
                              void* d_out, int out_size, void* d_ws, size_t ws_size,
                              hipStream_t stream) {
    const float* x        = (const float*)d_in[0];
    const float* offset_w = (const float*)d_in[1];
    const float* offset_b = (const float*)d_in[2];
    const float* mask_w   = (const float*)d_in[3];
    const float* mask_b   = (const float*)d_in[4];
    const float* conv_w   = (const float*)d_in[5];
    const float* bn_gamma = (const float*)d_in[6];
    const float* bn_beta  = (const float*)d_in[7];
    const float* bn_mean  = (const float*)d_in[8];
    const float* bn_var   = (const float*)d_in[9];

    char* ws = (char*)d_ws;
    size_t off = 0;
    ushort_t* xT   = (ushort_t*)(ws + off); off += (size_t)BB * HW * CC * 2;   // 13.1 MB
    float*    offs = (float*)(ws + off);    off += (size_t)BB * HW * 12 * 4;   //  4.9 MB
    ushort_t* cwBf = (ushort_t*)(ws + off); off += 64 * 64 * 2;
    float*    wmat = (float*)(ws + off);    off += 12 * 64 * 4;
    float*    wbias= (float*)(ws + off);    off += 64;
    float*    bnA  = (float*)(ws + off);    off += 64 * 4;
    float*    bnB  = (float*)(ws + off);    off += 64 * 4;

    prep_params<<<1, 256, 0, stream>>>(offset_w, offset_b, mask_w, mask_b, conv_w,
                                       bn_gamma, bn_beta, bn_mean, bn_var,
                                       wmat, wbias, cwBf, bnA, bnB);
    prep_x<<<BB * (HW / 64), 256, 0, stream>>>(x, wmat, wbias, xT, offs);
    dysample_main<<<dim3(HWS / 64, BB), 256, 0, stream>>>(xT, offs, cwBf, bnA, bnB,
                                                          (float*)d_out);
}